// Round 13
// baseline (168.319 us; speedup 1.0000x reference)
//
#include <hip/hip_runtime.h>
#include <math.h>

#define NRAYS 2048
#define TOT   128
#define INDS  16
#define HID   64
#define EPSF  1e-8f
#define MTOT  (NRAYS*TOT)
#define NTAB  128

typedef float f32x2 __attribute__((ext_vector_type(2)));
typedef float f32x4 __attribute__((ext_vector_type(4)));

__device__ __forceinline__ float softplus_f(float x) {
    return fmaxf(x, 0.0f) + __logf(1.0f + __expf(-fabsf(x)));
}
__device__ __forceinline__ float sigmoid_f(float x) {
    return 1.0f / (1.0f + __expf(-x));
}
__device__ __forceinline__ float tanh_fast(float x) {
    float e2 = __expf(2.0f * x);
    return 1.0f - 2.0f / (e2 + 1.0f);
}
__device__ __forceinline__ f32x2 pkmax(f32x2 a, f32x2 b) {
    f32x2 r; r.x = fmaxf(a.x, b.x); r.y = fmaxf(a.y, b.y); return r;
}
__device__ __forceinline__ f32x2 pkfma(f32x2 a, f32x2 b, f32x2 c) {
    return __builtin_elementwise_fma(a, b, c);
}
__device__ __forceinline__ f32x4 fma4(f32x4 a, f32x4 b, f32x4 c) {
    return __builtin_elementwise_fma(a, b, c);
}

// z_k = fma(j_k, span/16, fma(span, k/15 - 1/32, nears))
#define CK(i) ((float)(i)*(1.0f/15.0f) - 0.03125f)

#define MAKE_Z(jA, jB, kbase, nears, span)                                    \
    float s16 = (span) * (1.0f/16.0f);                                        \
    f32x2 z01, z23, z45, z67;                                                 \
    z01.x = fmaf((jA).x, s16, fmaf(span, CK((kbase)+0), nears));              \
    z01.y = fmaf((jA).y, s16, fmaf(span, CK((kbase)+1), nears));              \
    z23.x = fmaf((jA).z, s16, fmaf(span, CK((kbase)+2), nears));              \
    z23.y = fmaf((jA).w, s16, fmaf(span, CK((kbase)+3), nears));              \
    z45.x = fmaf((jB).x, s16, fmaf(span, CK((kbase)+4), nears));              \
    z45.y = fmaf((jB).y, s16, fmaf(span, CK((kbase)+5), nears));              \
    z67.x = fmaf((jB).z, s16, fmaf(span, CK((kbase)+6), nears));              \
    z67.y = fmaf((jB).w, s16, fmaf(span, CK((kbase)+7), nears));

// lerp the block density table at absolute coordinate zz
#define TAB_EVAL(zz, mx0, mx1, mx2)                                           \
    {                                                                         \
        float x = ((zz) - ztab0) * invh;                                      \
        x = fminf(fmaxf(x, 0.0f), (float)(NTAB-1) - 1e-3f);                   \
        int i = (int)x; float w = x - (float)i;                               \
        f32x4 Ta = sTab[i]; f32x4 Tb = sTab[i+1];                             \
        f32x4 wv = {w, w, w, w};                                              \
        f32x4 F = fma4(wv, Tb - Ta, Ta);                                      \
        mx0 = fmaxf(mx0, F.x); mx1 = fmaxf(mx1, F.y); mx2 = fmaxf(mx2, F.z);  \
    }

__device__ __forceinline__ void env_logv(
    const float* __restrict__ env_map,
    float px, float py, float pz,
    float& v0, float& v1, float& v2)
{
    float theta = atan2f(px, -pz) * (1.0f/3.14159265358979323846f);
    float acv = (fabsf(py) <= 1.0f) ? acosf(py) : 0.0f;  // nan_to_num(arccos)
    float phi = 0.63661977236758134308f * acv - 1.0f;    // 2/pi
    float ixf = ((theta + 1.0f)*256.0f - 1.0f)*0.5f;
    float iyf = ((phi   + 1.0f)*128.0f - 1.0f)*0.5f;
    float x0f = floorf(ixf), y0f = floorf(iyf);
    float wx = ixf - x0f, wy = iyf - y0f;
    v0 = 0.f; v1 = 0.f; v2 = 0.f;
    auto tap = [&](float xc, float yc, float w) {
        if (xc >= 0.0f && xc < 256.0f && yc >= 0.0f && yc < 128.0f) {
            int xi = (int)xc, yi = (int)yc;
            const float* e = env_map + yi*256 + xi;
            v0 += w * e[0];
            v1 += w * e[128*256];
            v2 += w * e[2*128*256];
        }
    };
    tap(x0f,      y0f,      (1.0f-wx)*(1.0f-wy));
    tap(x0f+1.0f, y0f,      wx*(1.0f-wy));
    tap(x0f,      y0f+1.0f, (1.0f-wx)*wy);
    tap(x0f+1.0f, y0f+1.0f, wx*wy);
}

// 256 threads/block = 1 ray; lane pair (2s,2s+1) shares sub-ray s.
// r11: depth-0 density from 128-pt LDS table of block-uniform F(z).
// r12: non-scattered depth-1 reuses F(t+z); scattered rays compacted.
// NEW (r13): pool pass redistributed as TEAM-OF-4 per entry (lane bits
// [1:0] = sample quarter, full j-loop per lane -> 256 sins/lane instead of
// 512, pure-max reduction via shfl_xor 1,2). r12's pair mapping left waves
// 2-3 idle (VALUBusy 57%, dur flat) — issue dropped but critical path
// didn't. Only teammates (tid&3)<2 accumulate rgb (keeps 2x counting).
__global__ __launch_bounds__(256)
void render_kernel(const float* __restrict__ rays_o,
                   const float* __restrict__ rays_d,
                   const float* __restrict__ env_map,
                   const float* __restrict__ Wd1,
                   const float* __restrict__ Wd2,
                   const float* __restrict__ Wf1,
                   const float* __restrict__ Ws,
                   const float* __restrict__ Wdir,
                   const float* __restrict__ Wrho,
                   const float* __restrict__ jitter,
                   const float* __restrict__ u_t,
                   const float* __restrict__ u_scatter,
                   const int*   __restrict__ channel,
                   float* __restrict__ out)
{
    const int ray  = blockIdx.x;
    const int tid  = threadIdx.x;
    const int s    = tid >> 1;
    const int half = tid & 1;
    const int m    = ray * TOT + s;
    const int kbase = half * 8;

    __shared__ f32x4 sAB[HID];     // {A,A,B,B}
    __shared__ f32x4 sW01[HID];    // {w20,w20,w21,w21}
    __shared__ f32x2 sW2[HID];     // {w22,w22}
    __shared__ f32x4 sPW[HID];     // {pw1x,pw1y,pw1z,w20} (w2 packed in .w)
    __shared__ f32x4 sM0[HID];     // {P, Q, ws0, ws1}
    __shared__ f32x4 sM1[HID];     // {ws2, wd0, wd1, wd2}
    __shared__ f32x4 sM2[HID];     // {wr0, wr1, wr2, 0}
    __shared__ f32x4 sTab[NTAB];   // {F0,F1,F2,0}
    __shared__ f32x4 sP0[TOT];     // pool: {ox,oy,oz,dx}
    __shared__ f32x4 sP1[TOT];     // pool: {dy,dz,thr0,thr1}
    __shared__ f32x2 sP2[TOT];     // pool: {thr2, (float)m}
    __shared__ float sEnvE[3];     // exp(env) at block-uniform exit point
    __shared__ int   sCnt;
    __shared__ float sred[4][3];

    // ---- prefetch per-thread globals ----
    const float4* j0p = (const float4*)(jitter + (size_t)m*INDS + kbase);
    float4 j0A = j0p[0], j0B = j0p[1];
    int   ch = channel[m];
    float ut = u_t[m];
    float us = u_scatter[m];

    float ox = rays_o[ray*3+0], oy = rays_o[ray*3+1], oz = rays_o[ray*3+2];
    float dx = rays_d[ray*3+0], dy = rays_d[ray*3+1], dz = rays_d[ray*3+2];

    if (tid == 0) sCnt = 0;
    // ---- per-block weight tables ----
    if (tid < HID) {
        const float INV2PI = 0.15915494309189535f;
        float w1x = Wd1[tid], w1y = Wd1[HID+tid], w1z = Wd1[2*HID+tid];
        float pw1x = w1x*INV2PI, pw1y = w1y*INV2PI, pw1z = w1z*INV2PI;
        float A = ox*pw1x + oy*pw1y + oz*pw1z;
        float B = dx*pw1x + dy*pw1y + dz*pw1z;
        float w20 = Wd2[3*tid], w21 = Wd2[3*tid+1], w22 = Wd2[3*tid+2];
        sAB[tid]  = (f32x4){A, A, B, B};
        sW01[tid] = (f32x4){w20, w20, w21, w21};
        sW2[tid]  = (f32x2){w22, w22};
        sPW[tid]  = (f32x4){pw1x, pw1y, pw1z, 0.0f};
        float f0 = Wf1[tid],       f1 = Wf1[HID+tid],   f2 = Wf1[2*HID+tid];
        float f3 = Wf1[3*HID+tid], f4 = Wf1[4*HID+tid], f5 = Wf1[5*HID+tid];
        float P = ox*f0 + oy*f1 + oz*f2 + dx*f3 + dy*f4 + dz*f5;
        float Q = dx*f0 + dy*f1 + dz*f2;
        sM0[tid] = (f32x4){P, Q, Ws[3*tid], Ws[3*tid+1]};
        sM1[tid] = (f32x4){Ws[3*tid+2], Wdir[3*tid], Wdir[3*tid+1], Wdir[3*tid+2]};
        sM2[tid] = (f32x4){Wrho[3*tid], Wrho[3*tid+1], Wrho[3*tid+2], 0.0f};
    }
    __syncthreads();

    // ---- block-uniform depth-0 geometry + density table + env ----
    float a0g = dx*dx + dy*dy + dz*dz;
    float b0g = 2.0f*(dx*ox + dy*oy + dz*oz);
    float c0g = (ox*ox + oy*oy + oz*oz) - 1.0f;
    float delta0 = b0g*b0g - 4.0f*a0g*c0g;
    bool alive = (delta0 > 0.0f);   // block-uniform

    float nears = 0.f, fars = 0.f, span = 0.f, ztab0 = 0.f, invh = 0.f;
    if (alive) {
        float sq = sqrtf(delta0);
        nears = fmaxf((-b0g - sq) / (2.0f*a0g), 0.001f);
        fars  = fmaxf((-b0g + sq) / (2.0f*a0g), 0.001f);
        span  = fars - nears;
        ztab0 = fmaf(-span, 0.03125f, nears);
        float width = span * 1.0625f;
        float hstep = width * (1.0f/(NTAB-1));
        invh = (float)(NTAB-1) / width;
        int p = tid >> 1;
        float zp = fmaf((float)p, hstep, ztab0);
        float f0 = 0.f, f1 = 0.f, f2 = 0.f;
        const int jb = half * 32;
        #pragma unroll 4
        for (int j = jb; j < jb + 32; ++j) {
            f32x4 ab  = sAB[j];
            f32x4 w01 = sW01[j];
            f32x2 w2  = sW2[j];
            float hv = __builtin_amdgcn_sinf(fmaf(zp, ab.z, ab.x));
            f0 = fmaf(hv, w01.x, f0);
            f1 = fmaf(hv, w01.z, f1);
            f2 = fmaf(hv, w2.x, f2);
        }
        f0 += __shfl_xor(f0, 1, 64);
        f1 += __shfl_xor(f1, 1, 64);
        f2 += __shfl_xor(f2, 1, 64);
        if (half == 0) sTab[p] = (f32x4){f0, f1, f2, 0.0f};
        if (tid == 0) {
            float v0,v1,v2;
            env_logv(env_map, fmaf(dx,fars,ox), fmaf(dy,fars,oy), fmaf(dz,fars,oz),
                     v0,v1,v2);
            sEnvE[0] = __expf(v0); sEnvE[1] = __expf(v1); sEnvE[2] = __expf(v2);
        }
    }
    __syncthreads();

    float thr0 = 1.f, thr1 = 1.f, thr2 = 1.f;
    float rgb0 = 0.f, rgb1 = 0.f, rgb2 = 0.f;
    bool  tab_d1 = false;
    float tadv = 0.f;

    // ================= depth 0 =================
    if (alive) {
        MAKE_Z(j0A, j0B, kbase, nears, span)
        float mx0 = -1e30f, mx1 = -1e30f, mx2 = -1e30f;
        TAB_EVAL(z01.x, mx0,mx1,mx2) TAB_EVAL(z01.y, mx0,mx1,mx2)
        TAB_EVAL(z23.x, mx0,mx1,mx2) TAB_EVAL(z23.y, mx0,mx1,mx2)
        TAB_EVAL(z45.x, mx0,mx1,mx2) TAB_EVAL(z45.y, mx0,mx1,mx2)
        TAB_EVAL(z67.x, mx0,mx1,mx2) TAB_EVAL(z67.y, mx0,mx1,mx2)
        mx0 = fmaxf(mx0, __shfl_xor(mx0, 1, 64));
        mx1 = fmaxf(mx1, __shfl_xor(mx1, 1, 64));
        mx2 = fmaxf(mx2, __shfl_xor(mx2, 1, 64));

        float maj0 = fmaxf(softplus_f(mx0), 0.001f);
        float maj1 = fmaxf(softplus_f(mx1), 0.001f);
        float maj2 = fmaxf(softplus_f(mx2), 0.001f);
        float mmax = fmaxf(fmaxf(maj0, maj1), maj2);

        float maj = (ch == 0) ? maj0 : ((ch == 1) ? maj1 : maj2);
        float t   = -log1pf(-ut) / maj + nears;

        if (t >= fars) {
            float den0 = __expf(-maj0*span)/(mmax+EPSF) + EPSF;
            float den1 = __expf(-maj1*span)/(mmax+EPSF) + EPSF;
            float den2 = __expf(-maj2*span)/(mmax+EPSF) + EPSF;
            float idm = 3.0f / (den0+den1+den2);
            rgb0 = den0*idm*sEnvE[0];
            rgb1 = den1*idm*sEnvE[1];
            rgb2 = den2*idm*sEnvE[2];
        } else {
            float tn  = t - nears;
            float imm = 1.0f / mmax;
            float tr0 = __expf(-maj0*tn) * imm;
            float tr1 = __expf(-maj1*tn) * imm;
            float tr2 = __expf(-maj2*tn) * imm;
            float i2m = 3.0f / (maj0*tr0 + maj1*tr1 + maj2*tr2);
            thr0 = tr0 * i2m;   // thr was 1
            thr1 = tr1 * i2m;
            thr2 = tr2 * i2m;
            ox = fmaf(dx, t, ox); oy = fmaf(dy, t, oy); oz = fmaf(dz, t, oz);

            // material MLP (DS-only; pre = P + t*Q)
            float st0=0.f, st1=0.f, st2=0.f;
            float dn0=0.f, dn1=0.f, dn2v=0.f;
            float rh0=0.f, rh1=0.f, rh2=0.f;
            const int j0 = half * 32;
            #pragma unroll 2
            for (int j = j0; j < j0 + 32; ++j) {
                f32x4 q0 = sM0[j];
                f32x4 q1 = sM1[j];
                f32x4 q2 = sM2[j];
                float pre = fmaf(t, q0.y, q0.x);
                float f = tanh_fast(pre);
                st0  = fmaf(f, q0.z, st0);
                st1  = fmaf(f, q0.w, st1);
                st2  = fmaf(f, q1.x, st2);
                dn0  = fmaf(f, q1.y, dn0);
                dn1  = fmaf(f, q1.z, dn1);
                dn2v = fmaf(f, q1.w, dn2v);
                rh0  = fmaf(f, q2.x, rh0);
                rh1  = fmaf(f, q2.y, rh1);
                rh2  = fmaf(f, q2.z, rh2);
            }
            st0  += __shfl_xor(st0, 1, 64);
            st1  += __shfl_xor(st1, 1, 64);
            st2  += __shfl_xor(st2, 1, 64);
            dn0  += __shfl_xor(dn0, 1, 64);
            dn1  += __shfl_xor(dn1, 1, 64);
            dn2v += __shfl_xor(dn2v, 1, 64);
            rh0  += __shfl_xor(rh0, 1, 64);
            rh1  += __shfl_xor(rh1, 1, 64);
            rh2  += __shfl_xor(rh2, 1, 64);

            float stch = (ch == 0) ? st0 : ((ch == 1) ? st1 : st2);
            float sp = fminf(softplus_f(stch) / maj, 1.0f);
            if (us < sp) {
                float inr = 1.0f / (sqrtf(dn0*dn0 + dn1*dn1 + dn2v*dn2v) + EPSF);
                float ndx = dn0*inr, ndy = dn1*inr, ndz = dn2v*inr;
                float isp = 1.0f/(sp + EPSF);
                float t0 = thr0 * isp * sigmoid_f(rh0);
                float t1 = thr1 * isp * sigmoid_f(rh1);
                float t2 = thr2 * isp * sigmoid_f(rh2);
                if (half == 0) {
                    int sl = atomicAdd(&sCnt, 1);
                    sP0[sl] = (f32x4){ox, oy, oz, ndx};
                    sP1[sl] = (f32x4){ndy, ndz, t0, t1};
                    sP2[sl] = (f32x2){t2, (float)m};
                }
            } else {
                float iv = 1.0f/(1.0f - sp + EPSF);
                thr0 *= iv; thr1 *= iv; thr2 *= iv;
                tab_d1 = true;
                tadv = t;
            }
        }
    }
    __syncthreads();
    int npool = sCnt;

    // ===== depth 1, non-scattered: d == d0 -> density = F(tadv + z) =====
    if (tab_d1) {
        float a1 = dx*dx + dy*dy + dz*dz;
        float b1 = 2.0f*(dx*ox + dy*oy + dz*oz);
        float c1 = (ox*ox + oy*oy + oz*oz) - 1.0f;
        float delta1 = b1*b1 - 4.0f*a1*c1;
        if (delta1 > 0.0f) {
            const float4* j1p = (const float4*)(jitter + ((size_t)MTOT + m)*INDS + kbase);
            float4 j1A = j1p[0], j1B = j1p[1];
            float sq1    = sqrtf(delta1);
            float nears1 = fmaxf((-b1 - sq1) / (2.0f*a1), 0.001f);
            float fars1  = fmaxf((-b1 + sq1) / (2.0f*a1), 0.001f);
            float span1  = fars1 - nears1;
            MAKE_Z(j1A, j1B, kbase, nears1, span1)
            float mx0 = -1e30f, mx1 = -1e30f, mx2 = -1e30f;
            TAB_EVAL(tadv + z01.x, mx0,mx1,mx2) TAB_EVAL(tadv + z01.y, mx0,mx1,mx2)
            TAB_EVAL(tadv + z23.x, mx0,mx1,mx2) TAB_EVAL(tadv + z23.y, mx0,mx1,mx2)
            TAB_EVAL(tadv + z45.x, mx0,mx1,mx2) TAB_EVAL(tadv + z45.y, mx0,mx1,mx2)
            TAB_EVAL(tadv + z67.x, mx0,mx1,mx2) TAB_EVAL(tadv + z67.y, mx0,mx1,mx2)
            mx0 = fmaxf(mx0, __shfl_xor(mx0, 1, 64));
            mx1 = fmaxf(mx1, __shfl_xor(mx1, 1, 64));
            mx2 = fmaxf(mx2, __shfl_xor(mx2, 1, 64));

            float maj0 = fmaxf(softplus_f(mx0), 0.001f);
            float maj1 = fmaxf(softplus_f(mx1), 0.001f);
            float maj2 = fmaxf(softplus_f(mx2), 0.001f);
            float mmax = fmaxf(fmaxf(maj0, maj1), maj2);

            float den0 = __expf(-maj0*span1)/(mmax+EPSF) + EPSF;
            float den1 = __expf(-maj1*span1)/(mmax+EPSF) + EPSF;
            float den2 = __expf(-maj2*span1)/(mmax+EPSF) + EPSF;
            float idm = 3.0f / (den0+den1+den2);
            rgb0 += thr0 * den0*idm*sEnvE[0];
            rgb1 += thr1 * den1*idm*sEnvE[1];
            rgb2 += thr2 * den2*idm*sEnvE[2];
        }
    }

    // ===== depth 1, scattered: compacted exact pass, TEAM-OF-4 =====
    {
        const int qlane = tid & 3;          // sample quarter
        const int kq    = qlane * 4;
        const float kqf = (float)kq;
        for (int q = tid >> 2; q < npool; q += 64) {
            f32x4 p0 = sP0[q];
            f32x4 p1 = sP1[q];
            f32x2 p2 = sP2[q];
            float pox = p0.x, poy = p0.y, poz = p0.z;
            float pdx = p0.w, pdy = p1.x, pdz = p1.y;
            float pt0 = p1.z, pt1 = p1.w, pt2 = p2.x;
            int   mm  = (int)p2.y;

            float a1 = pdx*pdx + pdy*pdy + pdz*pdz;
            float b1 = 2.0f*(pdx*pox + pdy*poy + pdz*poz);
            float c1 = (pox*pox + poy*poy + poz*poz) - 1.0f;
            float delta1 = b1*b1 - 4.0f*a1*c1;
            if (delta1 > 0.0f) {
                const float4* jp = (const float4*)(jitter + ((size_t)MTOT + mm)*INDS + kq);
                float4 jq = jp[0];           // 4 jitter values (L2-warm)
                float sq1    = sqrtf(delta1);
                float nears1 = fmaxf((-b1 - sq1) / (2.0f*a1), 0.001f);
                float fars1  = fmaxf((-b1 + sq1) / (2.0f*a1), 0.001f);
                float span1  = fars1 - nears1;
                float s16q   = span1 * (1.0f/16.0f);
                // z for this lane's 4 samples (runtime k base)
                f32x2 zA, zB;
                zA.x = fmaf(jq.x, s16q, fmaf(span1, (kqf+0.0f)*(1.0f/15.0f) - 0.03125f, nears1));
                zA.y = fmaf(jq.y, s16q, fmaf(span1, (kqf+1.0f)*(1.0f/15.0f) - 0.03125f, nears1));
                zB.x = fmaf(jq.z, s16q, fmaf(span1, (kqf+2.0f)*(1.0f/15.0f) - 0.03125f, nears1));
                zB.y = fmaf(jq.w, s16q, fmaf(span1, (kqf+3.0f)*(1.0f/15.0f) - 0.03125f, nears1));

                f32x2 a0A = {0.f,0.f}, a0B = {0.f,0.f};
                f32x2 a1A = {0.f,0.f}, a1B = {0.f,0.f};
                f32x2 a2A = {0.f,0.f}, a2B = {0.f,0.f};
                #pragma unroll 2
                for (int j = 0; j < HID; ++j) {
                    f32x4 pw  = sPW[j];
                    f32x4 w01 = sW01[j];
                    f32x2 w2  = sW2[j];
                    float A = fmaf(pox, pw.x, fmaf(poy, pw.y, poz*pw.z));
                    float B = fmaf(pdx, pw.x, fmaf(pdy, pw.y, pdz*pw.z));
                    f32x2 A2 = {A, A}, B2 = {B, B};
                    f32x2 gA = pkfma(zA, B2, A2);
                    f32x2 gB = pkfma(zB, B2, A2);
                    f32x2 hA, hB;
                    hA.x = __builtin_amdgcn_sinf(gA.x); hA.y = __builtin_amdgcn_sinf(gA.y);
                    hB.x = __builtin_amdgcn_sinf(gB.x); hB.y = __builtin_amdgcn_sinf(gB.y);
                    f32x2 W0 = {w01.x, w01.y}, W1 = {w01.z, w01.w};
                    a0A = pkfma(hA, W0, a0A); a0B = pkfma(hB, W0, a0B);
                    a1A = pkfma(hA, W1, a1A); a1B = pkfma(hB, W1, a1B);
                    a2A = pkfma(hA, w2, a2A); a2B = pkfma(hB, w2, a2B);
                }
                f32x2 pm0 = pkmax(a0A, a0B);
                f32x2 pm1 = pkmax(a1A, a1B);
                f32x2 pm2 = pkmax(a2A, a2B);
                float mx0 = fmaxf(pm0.x, pm0.y);
                float mx1 = fmaxf(pm1.x, pm1.y);
                float mx2 = fmaxf(pm2.x, pm2.y);
                // combine sample quarters across the team (bits 0,1)
                mx0 = fmaxf(mx0, __shfl_xor(mx0, 1, 64));
                mx1 = fmaxf(mx1, __shfl_xor(mx1, 1, 64));
                mx2 = fmaxf(mx2, __shfl_xor(mx2, 1, 64));
                mx0 = fmaxf(mx0, __shfl_xor(mx0, 2, 64));
                mx1 = fmaxf(mx1, __shfl_xor(mx1, 2, 64));
                mx2 = fmaxf(mx2, __shfl_xor(mx2, 2, 64));

                float maj0 = fmaxf(softplus_f(mx0), 0.001f);
                float maj1 = fmaxf(softplus_f(mx1), 0.001f);
                float maj2 = fmaxf(softplus_f(mx2), 0.001f);
                float mmax = fmaxf(fmaxf(maj0, maj1), maj2);

                float den0 = __expf(-maj0*span1)/(mmax+EPSF) + EPSF;
                float den1 = __expf(-maj1*span1)/(mmax+EPSF) + EPSF;
                float den2 = __expf(-maj2*span1)/(mmax+EPSF) + EPSF;
                float idm = 3.0f / (den0+den1+den2);
                float v0,v1,v2;
                env_logv(env_map, fmaf(pdx,fars1,pox), fmaf(pdy,fars1,poy),
                         fmaf(pdz,fars1,poz), v0,v1,v2);
                // 2 of 4 teammates add -> same 2x counting as the pair paths
                if (qlane < 2) {
                    rgb0 += pt0 * den0*idm*__expf(v0);
                    rgb1 += pt1 * den1*idm*__expf(v1);
                    rgb2 += pt2 * den2*idm*__expf(v2);
                }
            }
        }
    }

    // ---- reduction: each sub-ray counted x2 -> sum/256 == mean/128 ----
    float r0 = rgb0, r1 = rgb1, r2 = rgb2;
    #pragma unroll
    for (int off = 32; off > 0; off >>= 1) {
        r0 += __shfl_down(r0, off, 64);
        r1 += __shfl_down(r1, off, 64);
        r2 += __shfl_down(r2, off, 64);
    }
    int wave = tid >> 6;
    if ((tid & 63) == 0) {
        sred[wave][0] = r0; sred[wave][1] = r1; sred[wave][2] = r2;
    }
    __syncthreads();
    if (tid == 0) {
        out[ray*3+0] = (sred[0][0]+sred[1][0]+sred[2][0]+sred[3][0]) * (1.0f/256.0f);
        out[ray*3+1] = (sred[0][1]+sred[1][1]+sred[2][1]+sred[3][1]) * (1.0f/256.0f);
        out[ray*3+2] = (sred[0][2]+sred[1][2]+sred[2][2]+sred[3][2]) * (1.0f/256.0f);
    }
}

extern "C" void kernel_launch(void* const* d_in, const int* in_sizes, int n_in,
                              void* d_out, int out_size, void* d_ws, size_t ws_size,
                              hipStream_t stream) {
    const float* rays_o    = (const float*)d_in[0];
    const float* rays_d    = (const float*)d_in[1];
    const float* env_map   = (const float*)d_in[2];
    const float* Wd1       = (const float*)d_in[3];
    const float* Wd2       = (const float*)d_in[4];
    const float* Wf1       = (const float*)d_in[5];
    const float* Ws        = (const float*)d_in[6];
    const float* Wdir      = (const float*)d_in[7];
    const float* Wrho      = (const float*)d_in[8];
    const float* jitter    = (const float*)d_in[9];
    const float* u_t       = (const float*)d_in[10];
    const float* u_scatter = (const float*)d_in[11];
    const int*   channel   = (const int*)d_in[12];
    float* out = (float*)d_out;

    render_kernel<<<dim3(NRAYS), dim3(256), 0, stream>>>(
        rays_o, rays_d, env_map, Wd1, Wd2, Wf1, Ws, Wdir, Wrho,
        jitter, u_t, u_scatter, channel, out);
}

// Round 14
// 165.305 us; speedup vs baseline: 1.0182x; 1.0182x over previous
//
#include <hip/hip_runtime.h>
#include <math.h>

#define NRAYS 2048
#define TOT   128
#define INDS  16
#define HID   64
#define EPSF  1e-8f
#define MTOT  (NRAYS*TOT)
#define NTAB  128

typedef float f32x2 __attribute__((ext_vector_type(2)));
typedef float f32x4 __attribute__((ext_vector_type(4)));

__device__ __forceinline__ float softplus_f(float x) {
    return fmaxf(x, 0.0f) + __logf(1.0f + __expf(-fabsf(x)));
}
__device__ __forceinline__ float sigmoid_f(float x) {
    return 1.0f / (1.0f + __expf(-x));
}
__device__ __forceinline__ float tanh_fast(float x) {
    float e2 = __expf(2.0f * x);
    return 1.0f - 2.0f / (e2 + 1.0f);
}
__device__ __forceinline__ f32x2 pkmax(f32x2 a, f32x2 b) {
    f32x2 r; r.x = fmaxf(a.x, b.x); r.y = fmaxf(a.y, b.y); return r;
}
__device__ __forceinline__ f32x2 pkfma(f32x2 a, f32x2 b, f32x2 c) {
    return __builtin_elementwise_fma(a, b, c);
}

// z_k = fma(j_k, span/16, fma(span, k/15 - 1/32, nears))
#define CK(i) ((float)(i)*(1.0f/15.0f) - 0.03125f)

#define MAKE_Z(jA, jB, kbase, nears, span)                                    \
    float s16 = (span) * (1.0f/16.0f);                                        \
    f32x2 z01, z23, z45, z67;                                                 \
    z01.x = fmaf((jA).x, s16, fmaf(span, CK((kbase)+0), nears));              \
    z01.y = fmaf((jA).y, s16, fmaf(span, CK((kbase)+1), nears));              \
    z23.x = fmaf((jA).z, s16, fmaf(span, CK((kbase)+2), nears));              \
    z23.y = fmaf((jA).w, s16, fmaf(span, CK((kbase)+3), nears));              \
    z45.x = fmaf((jB).x, s16, fmaf(span, CK((kbase)+4), nears));              \
    z45.y = fmaf((jB).y, s16, fmaf(span, CK((kbase)+5), nears));              \
    z67.x = fmaf((jB).z, s16, fmaf(span, CK((kbase)+6), nears));              \
    z67.y = fmaf((jB).w, s16, fmaf(span, CK((kbase)+7), nears));

// lerp the 4-byte-stride table planes at absolute coordinate zz.
// r13's f32x4 table had 16B stride -> bank group = i%8 -> ~8-way conflicts
// on random lerp indices (7.26M SQ_LDS_BANK_CONFLICT). Scalar planes put
// random indices across all 32 banks (mean 2-way = free, m136).
#define TAB_EVAL(zz, mx0, mx1, mx2)                                           \
    {                                                                         \
        float x = ((zz) - ztab0) * invh;                                      \
        x = fminf(fmaxf(x, 0.0f), (float)(NTAB-1) - 1e-3f);                   \
        int i = (int)x; float w = x - (float)i;                               \
        float ta0 = sT0[i], tb0 = sT0[i+1];                                   \
        float ta1 = sT1[i], tb1 = sT1[i+1];                                   \
        float ta2 = sT2[i], tb2 = sT2[i+1];                                   \
        mx0 = fmaxf(mx0, fmaf(w, tb0 - ta0, ta0));                            \
        mx1 = fmaxf(mx1, fmaf(w, tb1 - ta1, ta1));                            \
        mx2 = fmaxf(mx2, fmaf(w, tb2 - ta2, ta2));                            \
    }

__device__ __forceinline__ void env_logv(
    const float* __restrict__ env_map,
    float px, float py, float pz,
    float& v0, float& v1, float& v2)
{
    float theta = atan2f(px, -pz) * (1.0f/3.14159265358979323846f);
    float acv = (fabsf(py) <= 1.0f) ? acosf(py) : 0.0f;  // nan_to_num(arccos)
    float phi = 0.63661977236758134308f * acv - 1.0f;    // 2/pi
    float ixf = ((theta + 1.0f)*256.0f - 1.0f)*0.5f;
    float iyf = ((phi   + 1.0f)*128.0f - 1.0f)*0.5f;
    float x0f = floorf(ixf), y0f = floorf(iyf);
    float wx = ixf - x0f, wy = iyf - y0f;
    v0 = 0.f; v1 = 0.f; v2 = 0.f;
    auto tap = [&](float xc, float yc, float w) {
        if (xc >= 0.0f && xc < 256.0f && yc >= 0.0f && yc < 128.0f) {
            int xi = (int)xc, yi = (int)yc;
            const float* e = env_map + yi*256 + xi;
            v0 += w * e[0];
            v1 += w * e[128*256];
            v2 += w * e[2*128*256];
        }
    };
    tap(x0f,      y0f,      (1.0f-wx)*(1.0f-wy));
    tap(x0f+1.0f, y0f,      wx*(1.0f-wy));
    tap(x0f,      y0f+1.0f, (1.0f-wx)*wy);
    tap(x0f+1.0f, y0f+1.0f, wx*wy);
}

// 256 threads/block = 1 ray; lane pair (2s,2s+1) shares sub-ray s.
// r11: depth-0 density via block-uniform F(z) table. r12: non-scattered
// depth-1 reuses F(t+z), block-uniform env. r13: scattered pool team-of-4.
// NEW (r14): table stored as 3 scalar planes (4B stride) to kill the
// 8-way bank conflicts of the 16B-stride f32x4 layout; log1pf -> __logf.
__global__ __launch_bounds__(256)
void render_kernel(const float* __restrict__ rays_o,
                   const float* __restrict__ rays_d,
                   const float* __restrict__ env_map,
                   const float* __restrict__ Wd1,
                   const float* __restrict__ Wd2,
                   const float* __restrict__ Wf1,
                   const float* __restrict__ Ws,
                   const float* __restrict__ Wdir,
                   const float* __restrict__ Wrho,
                   const float* __restrict__ jitter,
                   const float* __restrict__ u_t,
                   const float* __restrict__ u_scatter,
                   const int*   __restrict__ channel,
                   float* __restrict__ out)
{
    const int ray  = blockIdx.x;
    const int tid  = threadIdx.x;
    const int s    = tid >> 1;
    const int half = tid & 1;
    const int m    = ray * TOT + s;
    const int kbase = half * 8;

    __shared__ f32x4 sAB[HID];     // {A,A,B,B}
    __shared__ f32x4 sW01[HID];    // {w20,w20,w21,w21}
    __shared__ f32x2 sW2[HID];     // {w22,w22}
    __shared__ f32x4 sPW[HID];     // {pw1x,pw1y,pw1z,0}
    __shared__ f32x4 sM0[HID];     // {P, Q, ws0, ws1}
    __shared__ f32x4 sM1[HID];     // {ws2, wd0, wd1, wd2}
    __shared__ f32x4 sM2[HID];     // {wr0, wr1, wr2, 0}
    __shared__ float sT0[NTAB];    // density table, channel 0 (4B stride)
    __shared__ float sT1[NTAB];
    __shared__ float sT2[NTAB];
    __shared__ f32x4 sP0[TOT];     // pool: {ox,oy,oz,dx}
    __shared__ f32x4 sP1[TOT];     // pool: {dy,dz,thr0,thr1}
    __shared__ f32x2 sP2[TOT];     // pool: {thr2, (float)m}
    __shared__ float sEnvE[3];     // exp(env) at block-uniform exit point
    __shared__ int   sCnt;
    __shared__ float sred[4][3];

    // ---- prefetch per-thread globals ----
    const float4* j0p = (const float4*)(jitter + (size_t)m*INDS + kbase);
    float4 j0A = j0p[0], j0B = j0p[1];
    int   ch = channel[m];
    float ut = u_t[m];
    float us = u_scatter[m];

    float ox = rays_o[ray*3+0], oy = rays_o[ray*3+1], oz = rays_o[ray*3+2];
    float dx = rays_d[ray*3+0], dy = rays_d[ray*3+1], dz = rays_d[ray*3+2];

    if (tid == 0) sCnt = 0;
    // ---- per-block weight tables ----
    if (tid < HID) {
        const float INV2PI = 0.15915494309189535f;
        float w1x = Wd1[tid], w1y = Wd1[HID+tid], w1z = Wd1[2*HID+tid];
        float pw1x = w1x*INV2PI, pw1y = w1y*INV2PI, pw1z = w1z*INV2PI;
        float A = ox*pw1x + oy*pw1y + oz*pw1z;
        float B = dx*pw1x + dy*pw1y + dz*pw1z;
        float w20 = Wd2[3*tid], w21 = Wd2[3*tid+1], w22 = Wd2[3*tid+2];
        sAB[tid]  = (f32x4){A, A, B, B};
        sW01[tid] = (f32x4){w20, w20, w21, w21};
        sW2[tid]  = (f32x2){w22, w22};
        sPW[tid]  = (f32x4){pw1x, pw1y, pw1z, 0.0f};
        float f0 = Wf1[tid],       f1 = Wf1[HID+tid],   f2 = Wf1[2*HID+tid];
        float f3 = Wf1[3*HID+tid], f4 = Wf1[4*HID+tid], f5 = Wf1[5*HID+tid];
        float P = ox*f0 + oy*f1 + oz*f2 + dx*f3 + dy*f4 + dz*f5;
        float Q = dx*f0 + dy*f1 + dz*f2;
        sM0[tid] = (f32x4){P, Q, Ws[3*tid], Ws[3*tid+1]};
        sM1[tid] = (f32x4){Ws[3*tid+2], Wdir[3*tid], Wdir[3*tid+1], Wdir[3*tid+2]};
        sM2[tid] = (f32x4){Wrho[3*tid], Wrho[3*tid+1], Wrho[3*tid+2], 0.0f};
    }
    __syncthreads();

    // ---- block-uniform depth-0 geometry + density table + env ----
    float a0g = dx*dx + dy*dy + dz*dz;
    float b0g = 2.0f*(dx*ox + dy*oy + dz*oz);
    float c0g = (ox*ox + oy*oy + oz*oz) - 1.0f;
    float delta0 = b0g*b0g - 4.0f*a0g*c0g;
    bool alive = (delta0 > 0.0f);   // block-uniform

    float nears = 0.f, fars = 0.f, span = 0.f, ztab0 = 0.f, invh = 0.f;
    if (alive) {
        float sq = sqrtf(delta0);
        nears = fmaxf((-b0g - sq) / (2.0f*a0g), 0.001f);
        fars  = fmaxf((-b0g + sq) / (2.0f*a0g), 0.001f);
        span  = fars - nears;
        ztab0 = fmaf(-span, 0.03125f, nears);
        float width = span * 1.0625f;
        float hstep = width * (1.0f/(NTAB-1));
        invh = (float)(NTAB-1) / width;
        int p = tid >> 1;
        float zp = fmaf((float)p, hstep, ztab0);
        float f0 = 0.f, f1 = 0.f, f2 = 0.f;
        const int jb = half * 32;
        #pragma unroll 4
        for (int j = jb; j < jb + 32; ++j) {
            f32x4 ab  = sAB[j];
            f32x4 w01 = sW01[j];
            f32x2 w2  = sW2[j];
            float hv = __builtin_amdgcn_sinf(fmaf(zp, ab.z, ab.x));
            f0 = fmaf(hv, w01.x, f0);
            f1 = fmaf(hv, w01.z, f1);
            f2 = fmaf(hv, w2.x, f2);
        }
        f0 += __shfl_xor(f0, 1, 64);
        f1 += __shfl_xor(f1, 1, 64);
        f2 += __shfl_xor(f2, 1, 64);
        if (half == 0) { sT0[p] = f0; sT1[p] = f1; sT2[p] = f2; }
        if (tid == 0) {
            float v0,v1,v2;
            env_logv(env_map, fmaf(dx,fars,ox), fmaf(dy,fars,oy), fmaf(dz,fars,oz),
                     v0,v1,v2);
            sEnvE[0] = __expf(v0); sEnvE[1] = __expf(v1); sEnvE[2] = __expf(v2);
        }
    }
    __syncthreads();

    float thr0 = 1.f, thr1 = 1.f, thr2 = 1.f;
    float rgb0 = 0.f, rgb1 = 0.f, rgb2 = 0.f;
    bool  tab_d1 = false;
    float tadv = 0.f;

    // ================= depth 0 =================
    if (alive) {
        MAKE_Z(j0A, j0B, kbase, nears, span)
        float mx0 = -1e30f, mx1 = -1e30f, mx2 = -1e30f;
        TAB_EVAL(z01.x, mx0,mx1,mx2) TAB_EVAL(z01.y, mx0,mx1,mx2)
        TAB_EVAL(z23.x, mx0,mx1,mx2) TAB_EVAL(z23.y, mx0,mx1,mx2)
        TAB_EVAL(z45.x, mx0,mx1,mx2) TAB_EVAL(z45.y, mx0,mx1,mx2)
        TAB_EVAL(z67.x, mx0,mx1,mx2) TAB_EVAL(z67.y, mx0,mx1,mx2)
        mx0 = fmaxf(mx0, __shfl_xor(mx0, 1, 64));
        mx1 = fmaxf(mx1, __shfl_xor(mx1, 1, 64));
        mx2 = fmaxf(mx2, __shfl_xor(mx2, 1, 64));

        float maj0 = fmaxf(softplus_f(mx0), 0.001f);
        float maj1 = fmaxf(softplus_f(mx1), 0.001f);
        float maj2 = fmaxf(softplus_f(mx2), 0.001f);
        float mmax = fmaxf(fmaxf(maj0, maj1), maj2);

        float maj = (ch == 0) ? maj0 : ((ch == 1) ? maj1 : maj2);
        float t   = -__logf(1.0f - ut) / maj + nears;

        if (t >= fars) {
            float den0 = __expf(-maj0*span)/(mmax+EPSF) + EPSF;
            float den1 = __expf(-maj1*span)/(mmax+EPSF) + EPSF;
            float den2 = __expf(-maj2*span)/(mmax+EPSF) + EPSF;
            float idm = 3.0f / (den0+den1+den2);
            rgb0 = den0*idm*sEnvE[0];
            rgb1 = den1*idm*sEnvE[1];
            rgb2 = den2*idm*sEnvE[2];
        } else {
            float tn  = t - nears;
            float imm = 1.0f / mmax;
            float tr0 = __expf(-maj0*tn) * imm;
            float tr1 = __expf(-maj1*tn) * imm;
            float tr2 = __expf(-maj2*tn) * imm;
            float i2m = 3.0f / (maj0*tr0 + maj1*tr1 + maj2*tr2);
            thr0 = tr0 * i2m;   // thr was 1
            thr1 = tr1 * i2m;
            thr2 = tr2 * i2m;
            ox = fmaf(dx, t, ox); oy = fmaf(dy, t, oy); oz = fmaf(dz, t, oz);

            // material MLP (DS-only; pre = P + t*Q)
            float st0=0.f, st1=0.f, st2=0.f;
            float dn0=0.f, dn1=0.f, dn2v=0.f;
            float rh0=0.f, rh1=0.f, rh2=0.f;
            const int j0 = half * 32;
            #pragma unroll 2
            for (int j = j0; j < j0 + 32; ++j) {
                f32x4 q0 = sM0[j];
                f32x4 q1 = sM1[j];
                f32x4 q2 = sM2[j];
                float pre = fmaf(t, q0.y, q0.x);
                float f = tanh_fast(pre);
                st0  = fmaf(f, q0.z, st0);
                st1  = fmaf(f, q0.w, st1);
                st2  = fmaf(f, q1.x, st2);
                dn0  = fmaf(f, q1.y, dn0);
                dn1  = fmaf(f, q1.z, dn1);
                dn2v = fmaf(f, q1.w, dn2v);
                rh0  = fmaf(f, q2.x, rh0);
                rh1  = fmaf(f, q2.y, rh1);
                rh2  = fmaf(f, q2.z, rh2);
            }
            st0  += __shfl_xor(st0, 1, 64);
            st1  += __shfl_xor(st1, 1, 64);
            st2  += __shfl_xor(st2, 1, 64);
            dn0  += __shfl_xor(dn0, 1, 64);
            dn1  += __shfl_xor(dn1, 1, 64);
            dn2v += __shfl_xor(dn2v, 1, 64);
            rh0  += __shfl_xor(rh0, 1, 64);
            rh1  += __shfl_xor(rh1, 1, 64);
            rh2  += __shfl_xor(rh2, 1, 64);

            float stch = (ch == 0) ? st0 : ((ch == 1) ? st1 : st2);
            float sp = fminf(softplus_f(stch) / maj, 1.0f);
            if (us < sp) {
                float inr = 1.0f / (sqrtf(dn0*dn0 + dn1*dn1 + dn2v*dn2v) + EPSF);
                float ndx = dn0*inr, ndy = dn1*inr, ndz = dn2v*inr;
                float isp = 1.0f/(sp + EPSF);
                float t0 = thr0 * isp * sigmoid_f(rh0);
                float t1 = thr1 * isp * sigmoid_f(rh1);
                float t2 = thr2 * isp * sigmoid_f(rh2);
                if (half == 0) {
                    int sl = atomicAdd(&sCnt, 1);
                    sP0[sl] = (f32x4){ox, oy, oz, ndx};
                    sP1[sl] = (f32x4){ndy, ndz, t0, t1};
                    sP2[sl] = (f32x2){t2, (float)m};
                }
            } else {
                float iv = 1.0f/(1.0f - sp + EPSF);
                thr0 *= iv; thr1 *= iv; thr2 *= iv;
                tab_d1 = true;
                tadv = t;
            }
        }
    }
    __syncthreads();
    int npool = sCnt;

    // ===== depth 1, non-scattered: d == d0 -> density = F(tadv + z) =====
    if (tab_d1) {
        float a1 = dx*dx + dy*dy + dz*dz;
        float b1 = 2.0f*(dx*ox + dy*oy + dz*oz);
        float c1 = (ox*ox + oy*oy + oz*oz) - 1.0f;
        float delta1 = b1*b1 - 4.0f*a1*c1;
        if (delta1 > 0.0f) {
            const float4* j1p = (const float4*)(jitter + ((size_t)MTOT + m)*INDS + kbase);
            float4 j1A = j1p[0], j1B = j1p[1];
            float sq1    = sqrtf(delta1);
            float nears1 = fmaxf((-b1 - sq1) / (2.0f*a1), 0.001f);
            float fars1  = fmaxf((-b1 + sq1) / (2.0f*a1), 0.001f);
            float span1  = fars1 - nears1;
            MAKE_Z(j1A, j1B, kbase, nears1, span1)
            float mx0 = -1e30f, mx1 = -1e30f, mx2 = -1e30f;
            TAB_EVAL(tadv + z01.x, mx0,mx1,mx2) TAB_EVAL(tadv + z01.y, mx0,mx1,mx2)
            TAB_EVAL(tadv + z23.x, mx0,mx1,mx2) TAB_EVAL(tadv + z23.y, mx0,mx1,mx2)
            TAB_EVAL(tadv + z45.x, mx0,mx1,mx2) TAB_EVAL(tadv + z45.y, mx0,mx1,mx2)
            TAB_EVAL(tadv + z67.x, mx0,mx1,mx2) TAB_EVAL(tadv + z67.y, mx0,mx1,mx2)
            mx0 = fmaxf(mx0, __shfl_xor(mx0, 1, 64));
            mx1 = fmaxf(mx1, __shfl_xor(mx1, 1, 64));
            mx2 = fmaxf(mx2, __shfl_xor(mx2, 1, 64));

            float maj0 = fmaxf(softplus_f(mx0), 0.001f);
            float maj1 = fmaxf(softplus_f(mx1), 0.001f);
            float maj2 = fmaxf(softplus_f(mx2), 0.001f);
            float mmax = fmaxf(fmaxf(maj0, maj1), maj2);

            float den0 = __expf(-maj0*span1)/(mmax+EPSF) + EPSF;
            float den1 = __expf(-maj1*span1)/(mmax+EPSF) + EPSF;
            float den2 = __expf(-maj2*span1)/(mmax+EPSF) + EPSF;
            float idm = 3.0f / (den0+den1+den2);
            rgb0 += thr0 * den0*idm*sEnvE[0];
            rgb1 += thr1 * den1*idm*sEnvE[1];
            rgb2 += thr2 * den2*idm*sEnvE[2];
        }
    }

    // ===== depth 1, scattered: compacted exact pass, TEAM-OF-4 =====
    {
        const int qlane = tid & 3;          // sample quarter
        const int kq    = qlane * 4;
        const float kqf = (float)kq;
        for (int q = tid >> 2; q < npool; q += 64) {
            f32x4 p0 = sP0[q];
            f32x4 p1 = sP1[q];
            f32x2 p2 = sP2[q];
            float pox = p0.x, poy = p0.y, poz = p0.z;
            float pdx = p0.w, pdy = p1.x, pdz = p1.y;
            float pt0 = p1.z, pt1 = p1.w, pt2 = p2.x;
            int   mm  = (int)p2.y;

            float a1 = pdx*pdx + pdy*pdy + pdz*pdz;
            float b1 = 2.0f*(pdx*pox + pdy*poy + pdz*poz);
            float c1 = (pox*pox + poy*poy + poz*poz) - 1.0f;
            float delta1 = b1*b1 - 4.0f*a1*c1;
            if (delta1 > 0.0f) {
                const float4* jp = (const float4*)(jitter + ((size_t)MTOT + mm)*INDS + kq);
                float4 jq = jp[0];           // 4 jitter values (L2-warm)
                float sq1    = sqrtf(delta1);
                float nears1 = fmaxf((-b1 - sq1) / (2.0f*a1), 0.001f);
                float fars1  = fmaxf((-b1 + sq1) / (2.0f*a1), 0.001f);
                float span1  = fars1 - nears1;
                float s16q   = span1 * (1.0f/16.0f);
                f32x2 zA, zB;
                zA.x = fmaf(jq.x, s16q, fmaf(span1, (kqf+0.0f)*(1.0f/15.0f) - 0.03125f, nears1));
                zA.y = fmaf(jq.y, s16q, fmaf(span1, (kqf+1.0f)*(1.0f/15.0f) - 0.03125f, nears1));
                zB.x = fmaf(jq.z, s16q, fmaf(span1, (kqf+2.0f)*(1.0f/15.0f) - 0.03125f, nears1));
                zB.y = fmaf(jq.w, s16q, fmaf(span1, (kqf+3.0f)*(1.0f/15.0f) - 0.03125f, nears1));

                f32x2 a0A = {0.f,0.f}, a0B = {0.f,0.f};
                f32x2 a1A = {0.f,0.f}, a1B = {0.f,0.f};
                f32x2 a2A = {0.f,0.f}, a2B = {0.f,0.f};
                #pragma unroll 2
                for (int j = 0; j < HID; ++j) {
                    f32x4 pw  = sPW[j];
                    f32x4 w01 = sW01[j];
                    f32x2 w2  = sW2[j];
                    float A = fmaf(pox, pw.x, fmaf(poy, pw.y, poz*pw.z));
                    float B = fmaf(pdx, pw.x, fmaf(pdy, pw.y, pdz*pw.z));
                    f32x2 A2 = {A, A}, B2 = {B, B};
                    f32x2 gA = pkfma(zA, B2, A2);
                    f32x2 gB = pkfma(zB, B2, A2);
                    f32x2 hA, hB;
                    hA.x = __builtin_amdgcn_sinf(gA.x); hA.y = __builtin_amdgcn_sinf(gA.y);
                    hB.x = __builtin_amdgcn_sinf(gB.x); hB.y = __builtin_amdgcn_sinf(gB.y);
                    f32x2 W0 = {w01.x, w01.y}, W1 = {w01.z, w01.w};
                    a0A = pkfma(hA, W0, a0A); a0B = pkfma(hB, W0, a0B);
                    a1A = pkfma(hA, W1, a1A); a1B = pkfma(hB, W1, a1B);
                    a2A = pkfma(hA, w2, a2A); a2B = pkfma(hB, w2, a2B);
                }
                f32x2 pm0 = pkmax(a0A, a0B);
                f32x2 pm1 = pkmax(a1A, a1B);
                f32x2 pm2 = pkmax(a2A, a2B);
                float mx0 = fmaxf(pm0.x, pm0.y);
                float mx1 = fmaxf(pm1.x, pm1.y);
                float mx2 = fmaxf(pm2.x, pm2.y);
                mx0 = fmaxf(mx0, __shfl_xor(mx0, 1, 64));
                mx1 = fmaxf(mx1, __shfl_xor(mx1, 1, 64));
                mx2 = fmaxf(mx2, __shfl_xor(mx2, 1, 64));
                mx0 = fmaxf(mx0, __shfl_xor(mx0, 2, 64));
                mx1 = fmaxf(mx1, __shfl_xor(mx1, 2, 64));
                mx2 = fmaxf(mx2, __shfl_xor(mx2, 2, 64));

                float maj0 = fmaxf(softplus_f(mx0), 0.001f);
                float maj1 = fmaxf(softplus_f(mx1), 0.001f);
                float maj2 = fmaxf(softplus_f(mx2), 0.001f);
                float mmax = fmaxf(fmaxf(maj0, maj1), maj2);

                float den0 = __expf(-maj0*span1)/(mmax+EPSF) + EPSF;
                float den1 = __expf(-maj1*span1)/(mmax+EPSF) + EPSF;
                float den2 = __expf(-maj2*span1)/(mmax+EPSF) + EPSF;
                float idm = 3.0f / (den0+den1+den2);
                float v0,v1,v2;
                env_logv(env_map, fmaf(pdx,fars1,pox), fmaf(pdy,fars1,poy),
                         fmaf(pdz,fars1,poz), v0,v1,v2);
                if (qlane < 2) {
                    rgb0 += pt0 * den0*idm*__expf(v0);
                    rgb1 += pt1 * den1*idm*__expf(v1);
                    rgb2 += pt2 * den2*idm*__expf(v2);
                }
            }
        }
    }

    // ---- reduction: each sub-ray counted x2 -> sum/256 == mean/128 ----
    float r0 = rgb0, r1 = rgb1, r2 = rgb2;
    #pragma unroll
    for (int off = 32; off > 0; off >>= 1) {
        r0 += __shfl_down(r0, off, 64);
        r1 += __shfl_down(r1, off, 64);
        r2 += __shfl_down(r2, off, 64);
    }
    int wave = tid >> 6;
    if ((tid & 63) == 0) {
        sred[wave][0] = r0; sred[wave][1] = r1; sred[wave][2] = r2;
    }
    __syncthreads();
    if (tid == 0) {
        out[ray*3+0] = (sred[0][0]+sred[1][0]+sred[2][0]+sred[3][0]) * (1.0f/256.0f);
        out[ray*3+1] = (sred[0][1]+sred[1][1]+sred[2][1]+sred[3][1]) * (1.0f/256.0f);
        out[ray*3+2] = (sred[0][2]+sred[1][2]+sred[2][2]+sred[3][2]) * (1.0f/256.0f);
    }
}

extern "C" void kernel_launch(void* const* d_in, const int* in_sizes, int n_in,
                              void* d_out, int out_size, void* d_ws, size_t ws_size,
                              hipStream_t stream) {
    const float* rays_o    = (const float*)d_in[0];
    const float* rays_d    = (const float*)d_in[1];
    const float* env_map   = (const float*)d_in[2];
    const float* Wd1       = (const float*)d_in[3];
    const float* Wd2       = (const float*)d_in[4];
    const float* Wf1       = (const float*)d_in[5];
    const float* Ws        = (const float*)d_in[6];
    const float* Wdir      = (const float*)d_in[7];
    const float* Wrho      = (const float*)d_in[8];
    const float* jitter    = (const float*)d_in[9];
    const float* u_t       = (const float*)d_in[10];
    const float* u_scatter = (const float*)d_in[11];
    const int*   channel   = (const int*)d_in[12];
    float* out = (float*)d_out;

    render_kernel<<<dim3(NRAYS), dim3(256), 0, stream>>>(
        rays_o, rays_d, env_map, Wd1, Wd2, Wf1, Ws, Wdir, Wrho,
        jitter, u_t, u_scatter, channel, out);
}